// Round 1
// 360.345 us; speedup vs baseline: 1.1484x; 1.1484x over previous
//
#include <hip/hip_runtime.h>
#include <stdint.h>

// LSTM cell as one bf16-MFMA GEMM: M=65536, N=1024 (4 gates x 256), K=512 (x||h)
// Tile col map: c in [0,128): gate=(c>>4)&3, h = h0 + (c&15) + 16*(c>>6)
//  -> wave frag j == gate, lane m == h column  => register-only LSTM epilogue.
// R2: BK=64 (two 32-wide sub-tiles, 32 MFMA per barrier pair), XCD-aware block
//     remap (A-tile reuse stays in one XCD's L2), LDS-staged epilogue writing
//     full 128B lines (kills the 2x partial-line write amplification).
#define B_DIM 65536
#define HOFF  16777216   // B_DIM*256, offset of c_new in d_out

typedef __attribute__((ext_vector_type(8))) short short8;
typedef __attribute__((ext_vector_type(8))) unsigned short ushort8_t;
typedef __attribute__((ext_vector_type(4))) float f32x4;

__device__ __forceinline__ unsigned short f2bf(float f) {
  unsigned int u = __builtin_bit_cast(unsigned int, f);
  u += 0x7FFFu + ((u >> 16) & 1u);          // RNE
  return (unsigned short)(u >> 16);
}
__device__ __forceinline__ float sigf(float x) { return 1.0f / (1.0f + __expf(-x)); }
__device__ __forceinline__ float tanh_fast(float x) {
  float a = fabsf(x);
  float e = __expf(-2.0f * a);
  float t = (1.0f - e) / (1.0f + e);
  return x < 0.0f ? -t : t;
}

typedef const __attribute__((address_space(1))) unsigned int* as1p;
typedef __attribute__((address_space(3))) unsigned int* as3p;
__device__ __forceinline__ void llds16(const unsigned short* g, unsigned short* l) {
  __builtin_amdgcn_global_load_lds((as1p)g, (as3p)l, 16, 0, 0);
}

// ---- prep: fp32 -> bf16, 8 elems/thread, 16B-aligned loads/stores ----------
__global__ void prep_a(const float* __restrict__ x, const float* __restrict__ h,
                       ushort8_t* __restrict__ A8) {
  unsigned o = blockIdx.x * 256u + threadIdx.x;   // [0, B*64)
  unsigned b = o >> 6, c8 = o & 63u;
  const float* src = (c8 < 32u) ? x + (size_t)b * 256u + c8 * 8u
                                : h + (size_t)b * 256u + (c8 - 32u) * 8u;
  float4 v0 = *(const float4*)src;
  float4 v1 = *(const float4*)(src + 4);
  ushort8_t p;
  p[0] = f2bf(v0.x); p[1] = f2bf(v0.y); p[2] = f2bf(v0.z); p[3] = f2bf(v0.w);
  p[4] = f2bf(v1.x); p[5] = f2bf(v1.y); p[6] = f2bf(v1.z); p[7] = f2bf(v1.w);
  A8[o] = p;                                      // = A[b*512 + c8*8]
}

__global__ void prep_w(const float* __restrict__ Wi, const float* __restrict__ Wh,
                       ushort8_t* __restrict__ W8) {
  unsigned o = blockIdx.x * 256u + threadIdx.x;   // [0, 1024*64)
  unsigned n = o >> 6, c8 = o & 63u;
  const float* src = (c8 < 32u) ? Wi + (size_t)n * 256u + c8 * 8u
                                : Wh + (size_t)n * 256u + (c8 - 32u) * 8u;
  float4 v0 = *(const float4*)src;
  float4 v1 = *(const float4*)(src + 4);
  ushort8_t p;
  p[0] = f2bf(v0.x); p[1] = f2bf(v0.y); p[2] = f2bf(v0.z); p[3] = f2bf(v0.w);
  p[4] = f2bf(v1.x); p[5] = f2bf(v1.y); p[6] = f2bf(v1.z); p[7] = f2bf(v1.w);
  W8[o] = p;
}

// ---- fused GEMM + register LSTM epilogue -----------------------------------
// grid = (B/128)*8, 256 threads (4 waves, 2x2 over 128x128 tile), BK=64 as two
// 32-wide halves. Per half: LDS tile layout [row][4 slots x 16B],
// slot = chunk ^ ((row>>1)&3) (XOR swizzle applied via per-lane GLOBAL
// addresses so global_load_lds LDS side stays linear). Frag read bank-group =
// 4*(row&1) + (q^((m>>1)&3)) -> all 8 groups, 2-way = free.
// Block remap: xcd = bid&7 owns 64 consecutive b-tiles x 8 h-tiles so the 8
// N-split blocks sharing an A tile share one XCD's L2.
__global__ __launch_bounds__(256, 3) void lstm_gemm(
    const unsigned short* __restrict__ A,   // [B][512] bf16
    const unsigned short* __restrict__ W,   // [1024][512] bf16
    const float* __restrict__ cprev,
    const float* __restrict__ bi, const float* __restrict__ bh,
    float* __restrict__ out) {
  __shared__ __align__(16) char smem[32768];
  unsigned short* sA = (unsigned short*)smem;            // [2][128*32] = 16 KB
  unsigned short* sB = (unsigned short*)(smem + 16384);  // [2][128*32] = 16 KB

  const int t = threadIdx.x;
  const int wid = t >> 6, lane = t & 63;
  const int m = lane & 15, q = lane >> 4;

  // XCD-bijective remap: 4096 blocks = 8 xcd * (64 b-tiles * 8 h-tiles)
  const unsigned bid = blockIdx.x;
  const unsigned xcd = bid & 7u, kk_ = bid >> 3;         // kk_ in [0,512)
  const int b0 = (int)((xcd * 64u + (kk_ >> 3)) * 128u);
  const int h0 = (int)((kk_ & 7u) * 32u);

  const int R = (wid >> 1) * 64, Cc = (wid & 1) * 64;
  const int hcol = h0 + ((Cc >> 6) << 4) + m;     // this lane's h column

  // staging: per 32-wide half, 16 segs of 1KB (16 rows x 64B); wave owns segs
  // {2w,2w+1} of A and of B, for both halves.
  const int l4 = lane >> 2;
  const int sg0 = wid * 2, sg1 = wid * 2 + 1;
  const int r0 = sg0 * 16 + l4, r1 = sg1 * 16 + l4;       // tile row / tile col
  const int ck = ((lane & 3) ^ ((l4 >> 1) & 3)) * 8;      // swizzled k-chunk (ushorts)
  const unsigned aO0 = (unsigned)(b0 + r0) * 512u + (unsigned)ck;
  const unsigned aO1 = (unsigned)(b0 + r1) * 512u + (unsigned)ck;
  const int n0 = (((r0 >> 4) & 3) << 8) + h0 + (r0 & 15) + ((r0 >> 6) << 4);
  const int n1 = (((r1 >> 4) & 3) << 8) + h0 + (r1 & 15) + ((r1 >> 6) << 4);
  const unsigned wO0 = (unsigned)n0 * 512u + (unsigned)ck;
  const unsigned wO1 = (unsigned)n1 * 512u + (unsigned)ck;
  unsigned short* dA0 = sA + sg0 * 512;   // half 0 dests
  unsigned short* dA1 = sA + sg1 * 512;
  unsigned short* dB0 = sB + sg0 * 512;
  unsigned short* dB1 = sB + sg1 * 512;
  // half 1 dests are +4096 ushorts

  const int swz = (q ^ ((m >> 1) & 3)) * 8;       // frag-read slot offset (ushorts)

  // accumulators pre-seeded with bias (col = m fixed per lane; rows share bias)
  f32x4 acc[4][4];
#pragma unroll
  for (int j = 0; j < 4; ++j) {
    float bv = bi[(j << 8) + hcol] + bh[(j << 8) + hcol];
    f32x4 z = {bv, bv, bv, bv};
#pragma unroll
    for (int i = 0; i < 4; ++i) acc[i][j] = z;
  }

  for (int kt = 0; kt < 8; ++kt) {
    const unsigned k0 = kt * 64u;
    llds16(A + aO0 + k0, dA0);
    llds16(A + aO1 + k0, dA1);
    llds16(W + wO0 + k0, dB0);
    llds16(W + wO1 + k0, dB1);
    llds16(A + aO0 + k0 + 32u, dA0 + 4096);
    llds16(A + aO1 + k0 + 32u, dA1 + 4096);
    llds16(W + wO0 + k0 + 32u, dB0 + 4096);
    llds16(W + wO1 + k0 + 32u, dB1 + 4096);
    __syncthreads();
    {
      short8 av[4], bv[4];
#pragma unroll
      for (int i = 0; i < 4; ++i)
        av[i] = *(const short8*)&sA[(R + i * 16 + m) * 32 + swz];
#pragma unroll
      for (int j = 0; j < 4; ++j)
        bv[j] = *(const short8*)&sB[(Cc + j * 16 + m) * 32 + swz];
#pragma unroll
      for (int i = 0; i < 4; ++i)
#pragma unroll
        for (int j = 0; j < 4; ++j)
          acc[i][j] = __builtin_amdgcn_mfma_f32_16x16x32_bf16(av[i], bv[j], acc[i][j], 0, 0, 0);
    }
    {
      short8 av[4], bv[4];
#pragma unroll
      for (int i = 0; i < 4; ++i)
        av[i] = *(const short8*)&sA[4096 + (R + i * 16 + m) * 32 + swz];
#pragma unroll
      for (int j = 0; j < 4; ++j)
        bv[j] = *(const short8*)&sB[4096 + (Cc + j * 16 + m) * 32 + swz];
#pragma unroll
      for (int i = 0; i < 4; ++i)
#pragma unroll
        for (int j = 0; j < 4; ++j)
          acc[i][j] = __builtin_amdgcn_mfma_f32_16x16x32_bf16(av[i], bv[j], acc[i][j], 0, 0, 0);
    }
    __syncthreads();
  }

  // register epilogue: lane m holds gates j=0..3 for rows q*4+r of each i-block
  const float* cp = cprev + hcol;
  float hn[4][4], cn[4][4];
#pragma unroll
  for (int i = 0; i < 4; ++i) {
    const int br = b0 + R + i * 16 + (q << 2);
    float cv[4];
#pragma unroll
    for (int r = 0; r < 4; ++r) cv[r] = cp[(size_t)(br + r) << 8];
#pragma unroll
    for (int r = 0; r < 4; ++r) {
      float iv = sigf(acc[i][0][r]);
      float fv = sigf(acc[i][1][r]);
      float gv = tanh_fast(acc[i][2][r]);
      float ov = sigf(acc[i][3][r]);
      float c2 = fv * cv[r] + iv * gv;
      cn[i][r] = c2;
      hn[i][r] = ov * tanh_fast(c2);
    }
  }

  // LDS-staged stores: [128][36] fp32 tile (pad 36 -> 16B-aligned rows, 2-way
  // max bank aliasing). Cooperative write of full 128B lines: 8 thr x float4
  // per row. Two passes (h_new then c_new) reusing the dead GEMM LDS.
  float* ep = (float*)smem;                       // 128*36*4 = 18432 B
  const int ecol = ((Cc >> 6) << 4) + m;
#pragma unroll
  for (int i = 0; i < 4; ++i)
#pragma unroll
    for (int r = 0; r < 4; ++r)
      ep[(R + i * 16 + (q << 2) + r) * 36 + ecol] = hn[i][r];
  __syncthreads();
#pragma unroll
  for (int k = 0; k < 4; ++k) {
    const int id = t + k * 256;                   // [0,1024)
    const int row = id >> 3, c4 = id & 7;
    *(float4*)(out + ((size_t)(b0 + row) << 8) + h0 + c4 * 4) =
        *(const float4*)&ep[row * 36 + c4 * 4];
  }
  __syncthreads();
#pragma unroll
  for (int i = 0; i < 4; ++i)
#pragma unroll
    for (int r = 0; r < 4; ++r)
      ep[(R + i * 16 + (q << 2) + r) * 36 + ecol] = cn[i][r];
  __syncthreads();
#pragma unroll
  for (int k = 0; k < 4; ++k) {
    const int id = t + k * 256;
    const int row = id >> 3, c4 = id & 7;
    *(float4*)(out + HOFF + ((size_t)(b0 + row) << 8) + h0 + c4 * 4) =
        *(const float4*)&ep[row * 36 + c4 * 4];
  }
}

// ---- fallback (tiny workspace): correct but slow fp32 path -----------------
__global__ void lstm_naive(const float* __restrict__ x, const float* __restrict__ h,
                           const float* __restrict__ c,
                           const float* __restrict__ Wi, const float* __restrict__ Wh,
                           const float* __restrict__ bi, const float* __restrict__ bh,
                           float* __restrict__ out) {
  int gid = blockIdx.x * 256 + threadIdx.x;
  int b = gid >> 8, hh = gid & 255;
  float a0 = bi[hh] + bh[hh];
  float a1 = bi[256 + hh] + bh[256 + hh];
  float a2 = bi[512 + hh] + bh[512 + hh];
  float a3 = bi[768 + hh] + bh[768 + hh];
  const float* xr = x + (size_t)b * 256;
  const float* hr = h + (size_t)b * 256;
  const float* w0 = Wi + (size_t)hh * 256;
  const float* w1 = Wh + (size_t)hh * 256;
  for (int i = 0; i < 256; ++i) {
    float xv = xr[i];
    a0 += xv * w0[i]; a1 += xv * w0[65536 + i];
    a2 += xv * w0[131072 + i]; a3 += xv * w0[196608 + i];
  }
  for (int i = 0; i < 256; ++i) {
    float hv = hr[i];
    a0 += hv * w1[i]; a1 += hv * w1[65536 + i];
    a2 += hv * w1[131072 + i]; a3 += hv * w1[196608 + i];
  }
  float iv = sigf(a0), fv = sigf(a1), gv = tanh_fast(a2), ov = sigf(a3);
  float cn = fv * c[gid] + iv * gv;
  out[gid] = ov * tanh_fast(cn);
  out[HOFF + gid] = cn;
}

extern "C" void kernel_launch(void* const* d_in, const int* in_sizes, int n_in,
                              void* d_out, int out_size, void* d_ws, size_t ws_size,
                              hipStream_t stream) {
  const float* x  = (const float*)d_in[0];
  const float* h  = (const float*)d_in[1];
  const float* c  = (const float*)d_in[2];
  const float* Wi = (const float*)d_in[3];
  const float* Wh = (const float*)d_in[4];
  const float* bi = (const float*)d_in[5];
  const float* bh = (const float*)d_in[6];
  float* out = (float*)d_out;

  const size_t needA = (size_t)B_DIM * 512 * 2;   // 64 MB bf16 A = x||h
  const size_t needW = (size_t)1024 * 512 * 2;    // 1 MB bf16 W
  if (ws_size >= needA + needW) {
    ushort8_t* A8 = (ushort8_t*)d_ws;
    ushort8_t* W8 = (ushort8_t*)((char*)d_ws + needA);
    hipLaunchKernelGGL(prep_a, dim3(B_DIM * 64 / 256), dim3(256), 0, stream, x, h, A8);
    hipLaunchKernelGGL(prep_w, dim3(1024 * 64 / 256), dim3(256), 0, stream, Wi, Wh, W8);
    hipLaunchKernelGGL(lstm_gemm, dim3((B_DIM / 128) * 8), dim3(256), 0, stream,
                       (const unsigned short*)A8, (const unsigned short*)W8,
                       c, bi, bh, out);
  } else {
    hipLaunchKernelGGL(lstm_naive, dim3(B_DIM), dim3(256), 0, stream,
                       x, h, c, Wi, Wh, bi, bh, out);
  }
}